// Round 5
// baseline (10707.547 us; speedup 1.0000x reference)
//
#include <hip/hip_runtime.h>

// ============================================================================
// 2-layer LSTM (B=64,T=512,D=256,H=1024) + linear, fp32.
// Persistent kernel, diagonal pipeline (phase p = L0 step p || L1 step p-1),
// int16 weights/acts split into two int8 planes, 3x i8-MFMA per K=32.
// R5: compulsory-miss ring dedup. R3 was h-broadcast-bound (48MB/phase of
//     redundant MALL reads, serialized vmcnt(0) batches); R4's per-XCD copier
//     flags hung. Now h goes into a 512/513-slot ring: producers write-through
//     to MALL (sc0 sc1, proven R3), consumers use PLAIN cached loads — slot
//     addresses are virgin, so each XCD takes one compulsory L2 miss per line
//     (MALL-fresh) and the other ~31 WGs hit local L2. No flags, no s_getreg;
//     only the proven global all-gather barrier. Falls back to R3-style
//     2-slot ping-pong + sc0sc1 batch loads if ws_size < ~178MB.
// ============================================================================

#define T_STEPS 512
#define NWG 256
#define LDS_W     131072                  // [64 ksteps][2 planes][64 lanes][16B]
#define LDS_GBUF  (64 * 33 * 4)           // 8448, padded stride 33
#define LDS_CBUF  (64 * 9 * 4)            // 2304, padded stride 9
#define LDS_OFFS  (32 * 4)
#define SMEM_BYTES (LDS_W + LDS_GBUF + LDS_CBUF + LDS_OFFS)   // 141952
#define SLOT_ELEMS 65536                  // shorts per 128KB h slot

// workspace offsets (bytes)
#define OFF_SLOTS 0u                      // 256 x 64B arrival slots
#define OFF_H2F   0x40000u                // 256KB f32 h2 final
#define OFF_XQ    0x100000u               // 16MB i16 x
#define OFF_WIMG  0x1100000u              // 32MB weight images
#define OFF_H0R   0x3100000ull            // ring: 512 x 128KB = 64MB
#define OFF_H2R   0x7100000ull            // ring: 513 x 128KB = 64.125MB
#define WS_NEED   (OFF_H2R + 513ull * 131072ull)   // ~177.1MB
// compact fallback ring locations (2 slots each)
#define OFF_H0S   0x3100000ull
#define OFF_H2S   0x3140000ull

typedef int v2i  __attribute__((ext_vector_type(2)));
typedef int v4i  __attribute__((ext_vector_type(4)));
typedef int v16i __attribute__((ext_vector_type(16)));

__device__ __forceinline__ v16i zero16() {
    v16i z;
#pragma unroll
    for (int i = 0; i < 16; ++i) z[i] = 0;
    return z;
}

__device__ __forceinline__ void store_h8(short* p, v2i v) {    // write-through to MALL
    asm volatile("global_store_dwordx2 %0, %1, off sc0 sc1" :: "v"(p), "v"(v) : "memory");
}
__device__ __forceinline__ void waitcnt0() {
    asm volatile("s_waitcnt vmcnt(0)" ::: "memory");
}

// Split 16 i16 into hi/lo i8 planes + 3 int8 MFMAs (register-input variant).
__device__ __forceinline__ void kstep_r(v4i A0, v4i A1,
                                        const char* __restrict__ wl,
                                        v16i& ahh, v16i& amid)
{
    v4i HI, LO;
    HI.x = (int)__builtin_amdgcn_perm((unsigned)A0.y, (unsigned)A0.x, 0x07050301u);
    HI.y = (int)__builtin_amdgcn_perm((unsigned)A0.w, (unsigned)A0.z, 0x07050301u);
    HI.z = (int)__builtin_amdgcn_perm((unsigned)A1.y, (unsigned)A1.x, 0x07050301u);
    HI.w = (int)__builtin_amdgcn_perm((unsigned)A1.w, (unsigned)A1.z, 0x07050301u);
    LO.x = (int)(__builtin_amdgcn_perm((unsigned)A0.y, (unsigned)A0.x, 0x06040200u) ^ 0x80808080u);
    LO.y = (int)(__builtin_amdgcn_perm((unsigned)A0.w, (unsigned)A0.z, 0x06040200u) ^ 0x80808080u);
    LO.z = (int)(__builtin_amdgcn_perm((unsigned)A1.y, (unsigned)A1.x, 0x06040200u) ^ 0x80808080u);
    LO.w = (int)(__builtin_amdgcn_perm((unsigned)A1.w, (unsigned)A1.z, 0x06040200u) ^ 0x80808080u);
    v4i BH = *(const v4i*)wl;
    v4i BL = *(const v4i*)(wl + 1024);
    ahh  = __builtin_amdgcn_mfma_i32_32x32x32_i8(HI, BH, ahh, 0, 0, 0);
    amid = __builtin_amdgcn_mfma_i32_32x32x32_i8(HI, BL, amid, 0, 0, 0);
    amid = __builtin_amdgcn_mfma_i32_32x32x32_i8(LO, BH, amid, 0, 0, 0);
}

// plain cached loads (ring mode h, and x segment)
__device__ __forceinline__ void kstep(const short* __restrict__ ap,
                                      const char* __restrict__ wl,
                                      v16i& ahh, v16i& amid)
{
    v4i A0 = *(const v4i*)ap;
    v4i A1 = *(const v4i*)(ap + 8);
    kstep_r(A0, A1, wl, ahh, amid);
}

// fallback mode: 16x global_load_dwordx4 sc0 sc1 (MALL) + one waitcnt (R3-proven)
__device__ __forceinline__ void load_m16(const short* base, v4i* o) {
    asm volatile(
        "global_load_dwordx4 %0, %16, off sc0 sc1\n\t"
        "global_load_dwordx4 %1, %16, off offset:16 sc0 sc1\n\t"
        "global_load_dwordx4 %2, %16, off offset:64 sc0 sc1\n\t"
        "global_load_dwordx4 %3, %16, off offset:80 sc0 sc1\n\t"
        "global_load_dwordx4 %4, %16, off offset:128 sc0 sc1\n\t"
        "global_load_dwordx4 %5, %16, off offset:144 sc0 sc1\n\t"
        "global_load_dwordx4 %6, %16, off offset:192 sc0 sc1\n\t"
        "global_load_dwordx4 %7, %16, off offset:208 sc0 sc1\n\t"
        "global_load_dwordx4 %8, %16, off offset:256 sc0 sc1\n\t"
        "global_load_dwordx4 %9, %16, off offset:272 sc0 sc1\n\t"
        "global_load_dwordx4 %10, %16, off offset:320 sc0 sc1\n\t"
        "global_load_dwordx4 %11, %16, off offset:336 sc0 sc1\n\t"
        "global_load_dwordx4 %12, %16, off offset:384 sc0 sc1\n\t"
        "global_load_dwordx4 %13, %16, off offset:400 sc0 sc1\n\t"
        "global_load_dwordx4 %14, %16, off offset:448 sc0 sc1\n\t"
        "global_load_dwordx4 %15, %16, off offset:464 sc0 sc1\n\t"
        "s_waitcnt vmcnt(0)"
        : "=&v"(o[0]), "=&v"(o[1]), "=&v"(o[2]), "=&v"(o[3]),
          "=&v"(o[4]), "=&v"(o[5]), "=&v"(o[6]), "=&v"(o[7]),
          "=&v"(o[8]), "=&v"(o[9]), "=&v"(o[10]), "=&v"(o[11]),
          "=&v"(o[12]), "=&v"(o[13]), "=&v"(o[14]), "=&v"(o[15])
        : "v"(base)
        : "memory");
}

// ---------------------------------------------------------------------------
__global__ void quant_x(const float* __restrict__ x, short* __restrict__ xq, int n)
{
    int i = blockIdx.x * 256 + threadIdx.x;
    if (i < n) {
        float v = x[i] * 2048.f;
        v = fminf(fmaxf(v, -32767.f), 32767.f);
        xq[i] = (short)__float2int_rn(v);
    }
}

// prep: quantize + gate-reorder + fragment-tile weights into per-WG LDS images.
__global__ void quant_w(const float* __restrict__ wih0, const float* __restrict__ whh0,
                        const float* __restrict__ wih1, const float* __restrict__ whh1,
                        char* __restrict__ wimg)
{
    int gid = blockIdx.x * 256 + threadIdx.x;       // 256*64*64 = 1048576 threads
    if (gid >= 256 * 64 * 64) return;
    int lane = gid & 63;
    int s    = (gid >> 6) & 63;
    int wg   = gid >> 12;
    int layer = wg >> 7, nblk = wg & 127;
    int col = nblk * 32 + (lane & 31);
    int ro  = (col & 3) * 1024 + (col >> 2);        // original gate-blocked row
    int k0  = s * 32 + (lane >> 5) * 16;
    char* dst = wimg + (size_t)wg * LDS_W + s * 2048 + lane * 16;
#pragma unroll
    for (int j = 0; j < 16; ++j) {
        int k = k0 + j;
        float w = 0.f;
        if (layer == 0) {
            if (k < 256)       w = wih0[ro * 256 + k];
            else if (k < 1280) w = whh0[ro * 1024 + (k - 256)];
        } else {
            if (k < 1024)      w = wih1[ro * 1024 + k];
            else               w = whh1[ro * 1024 + (k - 1024)];
        }
        int q  = __float2int_rn(w * 524288.f);      // 2^19, |q|<=16384
        int hi = (q + 128) >> 8;
        int lo = q - (hi << 8);
        dst[j]        = (char)hi;
        dst[1024 + j] = (char)lo;
    }
}

// ---------------------------------------------------------------------------
// MALL=0: ring mode (plain cached h loads). MALL=1: fallback (sc0sc1 batches).
template<int MALL>
__global__ void __launch_bounds__(128) lstm_main(
    const short* __restrict__ xq, const char* __restrict__ wimg,
    const float* __restrict__ bih0, const float* __restrict__ bhh0,
    const float* __restrict__ bih1, const float* __restrict__ bhh1,
    short* __restrict__ h0r, short* __restrict__ h2r, int r0len, int r2len,
    float* __restrict__ h2f, unsigned* gslots)
{
    extern __shared__ char smem[];
    char*  wlds = smem;
    float* gbuf = (float*)(smem + LDS_W);                       // [64][33]
    float* cbuf = (float*)(smem + LDS_W + LDS_GBUF);            // [64][9]
    float* offs = (float*)(smem + LDS_W + LDS_GBUF + LDS_CBUF); // [32]

    const int wg    = blockIdx.x;
    const int layer = wg >> 7;
    const int nblk  = wg & 127;
    const int tid   = threadIdx.x;
    const int lane  = tid & 63;

    // stage this WG's weight image into LDS (128KB)
    {
        const v4i* src = (const v4i*)(wimg + (size_t)wg * LDS_W);
        v4i* dst = (v4i*)wlds;
        for (int i = tid; i < LDS_W / 16; i += 128) dst[i] = src[i];
    }
    for (int i = tid; i < 64 * 9; i += 128) cbuf[i] = 0.f;
    __syncthreads();

    // per-col constant: 128*colsum16*inv_scale (LO'=-128 bias comp) + gate bias
    if (tid < 32) {
        const int c  = tid;
        const int ns = (layer == 0) ? 40 : 64;
        int cs_x = 0, cs_h = 0;
        for (int s = 0; s < ns; ++s) {
            int sum = 0;
#pragma unroll
            for (int half = 0; half < 2; ++half) {
                const signed char* ph = (const signed char*)(wlds + s * 2048 + (half * 32 + c) * 16);
#pragma unroll
                for (int j = 0; j < 16; ++j)
                    sum += 256 * (int)ph[j] + (int)ph[1024 + j];
            }
            if (layer == 0 && s < 8) cs_x += sum; else cs_h += sum;
        }
        const int col = nblk * 32 + c;
        const int ro  = (col & 3) * 1024 + (col >> 2);
        const float bias = (layer == 0) ? (bih0[ro] + bhh0[ro]) : (bih1[ro] + bhh1[ro]);
        float off = 128.f * (float)cs_h * (1.f / 8589934592.f) + bias;   // /2^33
        if (layer == 0) off += 128.f * (float)cs_x * (1.f / 1073741824.f); // /2^30
        offs[c] = off;
    }
    __syncthreads();

    const int mrow = (tid >> 6) * 32 + (lane & 31);   // batch row of A fragment
    const int ksub = (lane >> 5) * 16;                // k sub-offset (i16 units)

    for (int p = 0; p <= T_STEPS; ++p) {
        const bool active = (layer == 0) ? (p < T_STEPS) : (p >= 1);

        // ---- L0: x projection first (no dependency on phase p-1) ----------
        float px[16];
        if (layer == 0 && active) {
            v16i ahh = zero16(), amid = zero16();
            const short* ax = xq + ((size_t)mrow * 512 + p) * 256 + ksub;
#pragma unroll
            for (int s = 0; s < 8; ++s)
                kstep(ax + s * 32, wlds + s * 2048 + lane * 16, ahh, amid);
#pragma unroll
            for (int r = 0; r < 16; ++r)
                px[r] = ((float)ahh[r] * 65536.f + (float)amid[r] * 256.f) * (1.f / 1073741824.f);
        }

        // ---- all-gather barrier wait: every slot >= p ---------------------
        if (p > 0) {
            const unsigned pp = (unsigned)p;
            const unsigned* s0 = gslots + (tid * 2) * 16;
            const unsigned* s1 = s0 + 16;
            while (__hip_atomic_load(s0, __ATOMIC_RELAXED, __HIP_MEMORY_SCOPE_AGENT) < pp)
                __builtin_amdgcn_s_sleep(1);
            while (__hip_atomic_load(s1, __ATOMIC_RELAXED, __HIP_MEMORY_SCOPE_AGENT) < pp)
                __builtin_amdgcn_s_sleep(1);
            __syncthreads();
            asm volatile("" ::: "memory");   // compiler fence: no load hoisting
        }

        if (active) {
            const int rs = (p > 0) ? (p - 1) : 0;
            const short* h0prev = h0r + (size_t)(rs % r0len) * SLOT_ELEMS + mrow * 1024 + ksub;
            float gates[16];
            v16i ahh = zero16(), amid = zero16();
            if (layer == 0) {
                // h segment (K=1024); h(-1)=0 -> skip at p=0
                if (p > 0) {
                    if (MALL) {
                        v4i hb[16];
                        for (int c = 0; c < 4; ++c) {
                            load_m16(h0prev + c * 256, hb);
#pragma unroll
                            for (int s = 0; s < 8; ++s)
                                kstep_r(hb[2 * s], hb[2 * s + 1],
                                        wlds + (8 + c * 8 + s) * 2048 + lane * 16, ahh, amid);
                        }
                    } else {
#pragma unroll 8
                        for (int s = 0; s < 32; ++s)
                            kstep(h0prev + s * 32, wlds + (8 + s) * 2048 + lane * 16, ahh, amid);
                    }
                }
#pragma unroll
                for (int r = 0; r < 16; ++r)
                    gates[r] = px[r]
                             + ((float)ahh[r] * 65536.f + (float)amid[r] * 256.f) * (1.f / 8589934592.f)
                             + offs[lane & 31];
            } else {
                // layer1: input h1 = h0(p-1) [slot p-1], recurrent h2(p-2) [slot p-1]
                const short* h2prev = h2r + (size_t)(rs % r2len) * SLOT_ELEMS + mrow * 1024 + ksub;
                if (MALL) {
                    v4i hb[16];
                    for (int c = 0; c < 4; ++c) {
                        load_m16(h0prev + c * 256, hb);
#pragma unroll
                        for (int s = 0; s < 8; ++s)
                            kstep_r(hb[2 * s], hb[2 * s + 1],
                                    wlds + (c * 8 + s) * 2048 + lane * 16, ahh, amid);
                    }
                    for (int c = 0; c < 4; ++c) {
                        load_m16(h2prev + c * 256, hb);
#pragma unroll
                        for (int s = 0; s < 8; ++s)
                            kstep_r(hb[2 * s], hb[2 * s + 1],
                                    wlds + (32 + c * 8 + s) * 2048 + lane * 16, ahh, amid);
                    }
                } else {
#pragma unroll 8
                    for (int s = 0; s < 32; ++s)
                        kstep(h0prev + s * 32, wlds + s * 2048 + lane * 16, ahh, amid);
#pragma unroll 8
                    for (int s = 0; s < 32; ++s)
                        kstep(h2prev + s * 32, wlds + (32 + s) * 2048 + lane * 16, ahh, amid);
                }
#pragma unroll
                for (int r = 0; r < 16; ++r)
                    gates[r] = ((float)ahh[r] * 65536.f + (float)amid[r] * 256.f) * (1.f / 8589934592.f)
                             + offs[lane & 31];
            }
            // scatter C/D frag to LDS: col=lane&31, row=(r&3)+8*(r>>2)+4*(lane>>5)
            {
                const int rbase = (tid >> 6) * 32 + 4 * (lane >> 5);
                const int c = lane & 31;
#pragma unroll
                for (int r = 0; r < 16; ++r) {
                    int row = rbase + (r & 3) + 8 * (r >> 2);
                    gbuf[row * 33 + c] = gates[r];
                }
            }
        }
        __syncthreads();
        if (active) {
            // state update: thread = (row, unit quad); one 8B MALL store each.
            short* hw = (layer == 0)
                      ? h0r + (size_t)(p % r0len) * SLOT_ELEMS
                      : h2r + (size_t)(p % r2len) * SLOT_ELEMS;
            const int r    = tid & 63;
            const int half = tid >> 6;
            unsigned hq[4];
            float hf[4];
#pragma unroll
            for (int j = 0; j < 4; ++j) {
                const int u = half * 4 + j;
                const float gi = gbuf[r * 33 + 4 * u + 0];
                const float gf = gbuf[r * 33 + 4 * u + 1];
                const float gg = gbuf[r * 33 + 4 * u + 2];
                const float go = gbuf[r * 33 + 4 * u + 3];
                const float i_ = 1.f / (1.f + __expf(-gi));
                const float f_ = 1.f / (1.f + __expf(-gf));
                const float g_ = 1.f - 2.f / (__expf(2.f * gg) + 1.f);
                const float o_ = 1.f / (1.f + __expf(-go));
                float c_ = f_ * cbuf[r * 9 + u] + i_ * g_;
                cbuf[r * 9 + u] = c_;
                const float h_ = o_ * (1.f - 2.f / (__expf(2.f * c_) + 1.f));
                hq[j] = (unsigned)(unsigned short)(short)__float2int_rn(h_ * 16384.f);
                hf[j] = h_;
            }
            v2i pk;
            pk.x = (int)(hq[0] | (hq[1] << 16));
            pk.y = (int)(hq[2] | (hq[3] << 16));
            const int jg = nblk * 8 + half * 4;
            store_h8(hw + r * 1024 + jg, pk);
            if (layer == 1 && p == T_STEPS) {
#pragma unroll
                for (int j = 0; j < 4; ++j) h2f[r * 1024 + jg + j] = hf[j];
            }
        }
        // ---- arrival: own stores to MALL, then signal p+1 -----------------
        waitcnt0();
        __syncthreads();
        if (tid == 0)
            __hip_atomic_store(gslots + wg * 16, (unsigned)(p + 1),
                               __ATOMIC_RELAXED, __HIP_MEMORY_SCOPE_AGENT);
    }
}

// ---------------------------------------------------------------------------
__global__ void final_lin(const float* __restrict__ h2f, const float* __restrict__ wlin,
                          const float* __restrict__ blin, float* __restrict__ out)
{
    const int b = blockIdx.x;
    const int l = threadIdx.x;
    float s = 0.f;
    for (int j = l; j < 1024; j += 64) s += h2f[b * 1024 + j] * wlin[j];
#pragma unroll
    for (int off = 32; off; off >>= 1) s += __shfl_down(s, off);
    if (l == 0) out[b] = s + blin[0];
}

// ---------------------------------------------------------------------------
extern "C" void kernel_launch(void* const* d_in, const int* in_sizes, int n_in,
                              void* d_out, int out_size, void* d_ws, size_t ws_size,
                              hipStream_t stream)
{
    const float* x    = (const float*)d_in[0];
    const float* wih0 = (const float*)d_in[1];
    const float* whh0 = (const float*)d_in[2];
    const float* bih0 = (const float*)d_in[3];
    const float* bhh0 = (const float*)d_in[4];
    const float* wih1 = (const float*)d_in[5];
    const float* whh1 = (const float*)d_in[6];
    const float* bih1 = (const float*)d_in[7];
    const float* bhh1 = (const float*)d_in[8];
    const float* wlin = (const float*)d_in[9];
    const float* blin = (const float*)d_in[10];

    char* ws = (char*)d_ws;
    unsigned* gslots = (unsigned*)(ws + OFF_SLOTS);
    float* h2f = (float*)(ws + OFF_H2F);
    short* xq  = (short*)(ws + OFF_XQ);
    char*  wimg = ws + OFF_WIMG;

    const bool ring = (ws_size >= WS_NEED);
    short* h0r = (short*)(ws + (ring ? OFF_H0R : OFF_H0S));
    short* h2r = (short*)(ws + (ring ? OFF_H2R : OFF_H2S));
    const int r0len = ring ? 512 : 2;
    const int r2len = ring ? 513 : 2;

    // zero arrival slots + h2 ring slot 0 (= h2(-1) zeros); ws is 0xAA-poisoned
    hipMemsetAsync(gslots, 0, 16384, stream);
    hipMemsetAsync(h2r, 0, 131072, stream);

    quant_x<<<32768, 256, 0, stream>>>(x, xq, 64 * 512 * 256);
    quant_w<<<4096, 256, 0, stream>>>(wih0, whh0, wih1, whh1, wimg);

    hipFuncSetAttribute((const void*)lstm_main<0>,
        hipFuncAttributeMaxDynamicSharedMemorySize, SMEM_BYTES);
    hipFuncSetAttribute((const void*)lstm_main<1>,
        hipFuncAttributeMaxDynamicSharedMemorySize, SMEM_BYTES);

    if (ring)
        lstm_main<0><<<NWG, 128, SMEM_BYTES, stream>>>(xq, wimg, bih0, bhh0, bih1, bhh1,
                                                       h0r, h2r, r0len, r2len, h2f, gslots);
    else
        lstm_main<1><<<NWG, 128, SMEM_BYTES, stream>>>(xq, wimg, bih0, bhh0, bih1, bhh1,
                                                       h0r, h2r, r0len, r2len, h2f, gslots);

    final_lin<<<64, 64, 0, stream>>>(h2f, wlin, blin, (float*)d_out);
}

// Round 7
// 6397.057 us; speedup vs baseline: 1.6738x; 1.6738x over previous
//
#include <hip/hip_runtime.h>

// ============================================================================
// 2-layer LSTM (B=64,T=512,D=256,H=1024) + linear, fp32.
// Persistent kernel, diagonal pipeline (phase p = L0 step p || L1 step p-1),
// int16 weights/acts split into two int8 planes, 3x i8-MFMA per K=32.
// R7 = R3 (proven, 7.4ms) + WG-local latency pipelining only:
//  - h loads double-buffered: issue batch c+1 (16x dwordx4 sc0sc1) before
//    consuming batch c; s_waitcnt vmcnt(16) register-bound to the buffer so
//    the compiler cannot consume before the HW wait.
//  - split-phase barrier (arrival at end, master-gather wait at start; both
//    R3/R5-proven) with L0's x-projection hoisted before the wait.
// No new cross-WG protocols (R4/R6 lesson: those failed unexplained).
// ============================================================================

#define T_STEPS 512
#define NWG 256
#define LDS_W     131072                  // [64 ksteps][2 planes][64 lanes][16B]
#define LDS_GBUF  (64 * 33 * 4)           // 8448, padded stride 33
#define LDS_CBUF  (64 * 9 * 4)            // 2304, padded stride 9
#define LDS_OFFS  (32 * 4)
#define SMEM_BYTES (LDS_W + LDS_GBUF + LDS_CBUF + LDS_OFFS)   // 141952

typedef int v2i  __attribute__((ext_vector_type(2)));
typedef int v4i  __attribute__((ext_vector_type(4)));
typedef int v16i __attribute__((ext_vector_type(16)));

__device__ __forceinline__ v16i zero16() {
    v16i z;
#pragma unroll
    for (int i = 0; i < 16; ++i) z[i] = 0;
    return z;
}

// 16x global_load_dwordx4 sc0 sc1 (MALL-direct), NO trailing wait.
__device__ __forceinline__ void load_h16_nw(const short* base, v4i* o) {
    asm volatile(
        "global_load_dwordx4 %0, %16, off sc0 sc1\n\t"
        "global_load_dwordx4 %1, %16, off offset:16 sc0 sc1\n\t"
        "global_load_dwordx4 %2, %16, off offset:64 sc0 sc1\n\t"
        "global_load_dwordx4 %3, %16, off offset:80 sc0 sc1\n\t"
        "global_load_dwordx4 %4, %16, off offset:128 sc0 sc1\n\t"
        "global_load_dwordx4 %5, %16, off offset:144 sc0 sc1\n\t"
        "global_load_dwordx4 %6, %16, off offset:192 sc0 sc1\n\t"
        "global_load_dwordx4 %7, %16, off offset:208 sc0 sc1\n\t"
        "global_load_dwordx4 %8, %16, off offset:256 sc0 sc1\n\t"
        "global_load_dwordx4 %9, %16, off offset:272 sc0 sc1\n\t"
        "global_load_dwordx4 %10, %16, off offset:320 sc0 sc1\n\t"
        "global_load_dwordx4 %11, %16, off offset:336 sc0 sc1\n\t"
        "global_load_dwordx4 %12, %16, off offset:384 sc0 sc1\n\t"
        "global_load_dwordx4 %13, %16, off offset:400 sc0 sc1\n\t"
        "global_load_dwordx4 %14, %16, off offset:448 sc0 sc1\n\t"
        "global_load_dwordx4 %15, %16, off offset:464 sc0 sc1"
        : "=&v"(o[0]), "=&v"(o[1]), "=&v"(o[2]), "=&v"(o[3]),
          "=&v"(o[4]), "=&v"(o[5]), "=&v"(o[6]), "=&v"(o[7]),
          "=&v"(o[8]), "=&v"(o[9]), "=&v"(o[10]), "=&v"(o[11]),
          "=&v"(o[12]), "=&v"(o[13]), "=&v"(o[14]), "=&v"(o[15])
        : "v"(base)
        : "memory");
}

// s_waitcnt vmcnt(N) with the buffer bound as in/out so consumers of b[]
// are data-dependent on the wait (compiler cannot hoist past it).
#define WAIT_BIND(cntstr, b)                                                   \
    asm volatile("s_waitcnt vmcnt(" cntstr ")"                                 \
        : "+v"((b)[0]), "+v"((b)[1]), "+v"((b)[2]), "+v"((b)[3]),              \
          "+v"((b)[4]), "+v"((b)[5]), "+v"((b)[6]), "+v"((b)[7]),              \
          "+v"((b)[8]), "+v"((b)[9]), "+v"((b)[10]), "+v"((b)[11]),            \
          "+v"((b)[12]), "+v"((b)[13]), "+v"((b)[14]), "+v"((b)[15])           \
        :: "memory")

__device__ __forceinline__ void store_h8(short* p, v2i v) {    // write-through MALL
    asm volatile("global_store_dwordx2 %0, %1, off sc0 sc1" :: "v"(p), "v"(v) : "memory");
}
__device__ __forceinline__ void waitcnt0() {
    asm volatile("s_waitcnt vmcnt(0)" ::: "memory");
}

__device__ __forceinline__ void split_a(v4i A0, v4i A1, v4i& HI, v4i& LO) {
    HI.x = (int)__builtin_amdgcn_perm((unsigned)A0.y, (unsigned)A0.x, 0x07050301u);
    HI.y = (int)__builtin_amdgcn_perm((unsigned)A0.w, (unsigned)A0.z, 0x07050301u);
    HI.z = (int)__builtin_amdgcn_perm((unsigned)A1.y, (unsigned)A1.x, 0x07050301u);
    HI.w = (int)__builtin_amdgcn_perm((unsigned)A1.w, (unsigned)A1.z, 0x07050301u);
    LO.x = (int)(__builtin_amdgcn_perm((unsigned)A0.y, (unsigned)A0.x, 0x06040200u) ^ 0x80808080u);
    LO.y = (int)(__builtin_amdgcn_perm((unsigned)A0.w, (unsigned)A0.z, 0x06040200u) ^ 0x80808080u);
    LO.z = (int)(__builtin_amdgcn_perm((unsigned)A1.y, (unsigned)A1.x, 0x06040200u) ^ 0x80808080u);
    LO.w = (int)(__builtin_amdgcn_perm((unsigned)A1.w, (unsigned)A1.z, 0x06040200u) ^ 0x80808080u);
}

// consume one 8-kstep batch from register buffer hb against weights at wbase
__device__ __forceinline__ void consume8(const v4i* hb, const char* wbase,
                                         v16i& ahh, v16i& amid)
{
#pragma unroll
    for (int s = 0; s < 8; ++s) {
        v4i HI, LO; split_a(hb[2 * s], hb[2 * s + 1], HI, LO);
        v4i BH = *(const v4i*)(wbase + s * 2048);
        v4i BL = *(const v4i*)(wbase + s * 2048 + 1024);
        ahh  = __builtin_amdgcn_mfma_i32_32x32x32_i8(HI, BH, ahh, 0, 0, 0);
        amid = __builtin_amdgcn_mfma_i32_32x32x32_i8(HI, BL, amid, 0, 0, 0);
        amid = __builtin_amdgcn_mfma_i32_32x32x32_i8(LO, BH, amid, 0, 0, 0);
    }
}

// plain cached-load kstep (x segment only)
__device__ __forceinline__ void kstep(const short* __restrict__ ap,
                                      const char* __restrict__ wl,
                                      v16i& ahh, v16i& amid)
{
    v4i A0 = *(const v4i*)ap;
    v4i A1 = *(const v4i*)(ap + 8);
    v4i HI, LO; split_a(A0, A1, HI, LO);
    v4i BH = *(const v4i*)wl;
    v4i BL = *(const v4i*)(wl + 1024);
    ahh  = __builtin_amdgcn_mfma_i32_32x32x32_i8(HI, BH, ahh, 0, 0, 0);
    amid = __builtin_amdgcn_mfma_i32_32x32x32_i8(HI, BL, amid, 0, 0, 0);
    amid = __builtin_amdgcn_mfma_i32_32x32x32_i8(LO, BH, amid, 0, 0, 0);
}

// ---------------------------------------------------------------------------
__global__ void quant_x(const float* __restrict__ x, short* __restrict__ xq, int n)
{
    int i = blockIdx.x * 256 + threadIdx.x;
    if (i < n) {
        float v = x[i] * 2048.f;
        v = fminf(fmaxf(v, -32767.f), 32767.f);
        xq[i] = (short)__float2int_rn(v);
    }
}

// prep: quantize + gate-reorder + fragment-tile weights into per-WG LDS images.
__global__ void quant_w(const float* __restrict__ wih0, const float* __restrict__ whh0,
                        const float* __restrict__ wih1, const float* __restrict__ whh1,
                        char* __restrict__ wimg)
{
    int gid = blockIdx.x * 256 + threadIdx.x;       // 256*64*64 = 1048576 threads
    if (gid >= 256 * 64 * 64) return;
    int lane = gid & 63;
    int s    = (gid >> 6) & 63;
    int wg   = gid >> 12;
    int layer = wg >> 7, nblk = wg & 127;
    int col = nblk * 32 + (lane & 31);
    int ro  = (col & 3) * 1024 + (col >> 2);        // original gate-blocked row
    int k0  = s * 32 + (lane >> 5) * 16;
    char* dst = wimg + (size_t)wg * LDS_W + s * 2048 + lane * 16;
#pragma unroll
    for (int j = 0; j < 16; ++j) {
        int k = k0 + j;
        float w = 0.f;
        if (layer == 0) {
            if (k < 256)       w = wih0[ro * 256 + k];
            else if (k < 1280) w = whh0[ro * 1024 + (k - 256)];
        } else {
            if (k < 1024)      w = wih1[ro * 1024 + k];
            else               w = whh1[ro * 1024 + (k - 1024)];
        }
        int q  = __float2int_rn(w * 524288.f);      // 2^19, |q|<=16384
        int hi = (q + 128) >> 8;
        int lo = q - (hi << 8);
        dst[j]        = (char)hi;
        dst[1024 + j] = (char)lo;
    }
}

// ---------------------------------------------------------------------------
__global__ void __launch_bounds__(128) lstm_main(
    const short* __restrict__ xq, const char* __restrict__ wimg,
    const float* __restrict__ bih0, const float* __restrict__ bhh0,
    const float* __restrict__ bih1, const float* __restrict__ bhh1,
    short* __restrict__ h0q, short* __restrict__ h2q,
    float* __restrict__ h2f, unsigned* gslots, unsigned* gbcast)
{
    extern __shared__ char smem[];
    char*  wlds = smem;
    float* gbuf = (float*)(smem + LDS_W);                       // [64][33]
    float* cbuf = (float*)(smem + LDS_W + LDS_GBUF);            // [64][9]
    float* offs = (float*)(smem + LDS_W + LDS_GBUF + LDS_CBUF); // [32]

    const int wg    = blockIdx.x;
    const int layer = wg >> 7;
    const int nblk  = wg & 127;
    const int tid   = threadIdx.x;
    const int lane  = tid & 63;
    const float inv30 = 9.313225746154785e-10f;   // 2^-30
    const float inv33 = 1.1641532182693481e-10f;  // 2^-33

    // stage this WG's weight image into LDS (128KB)
    {
        const v4i* src = (const v4i*)(wimg + (size_t)wg * LDS_W);
        v4i* dst = (v4i*)wlds;
        for (int i = tid; i < LDS_W / 16; i += 128) dst[i] = src[i];
    }
    for (int i = tid; i < 64 * 9; i += 128) cbuf[i] = 0.f;
    __syncthreads();

    // per-col constant: 128*colsum16*inv_scale (LO'=-128 bias comp) + gate bias
    if (tid < 32) {
        const int c  = tid;
        const int ns = (layer == 0) ? 40 : 64;
        int cs_x = 0, cs_h = 0;
        for (int s = 0; s < ns; ++s) {
            int sum = 0;
#pragma unroll
            for (int half = 0; half < 2; ++half) {
                const signed char* ph = (const signed char*)(wlds + s * 2048 + (half * 32 + c) * 16);
#pragma unroll
                for (int j = 0; j < 16; ++j)
                    sum += 256 * (int)ph[j] + (int)ph[1024 + j];
            }
            if (layer == 0 && s < 8) cs_x += sum; else cs_h += sum;
        }
        const int col = nblk * 32 + c;
        const int ro  = (col & 3) * 1024 + (col >> 2);
        const float bias = (layer == 0) ? (bih0[ro] + bhh0[ro]) : (bih1[ro] + bhh1[ro]);
        float off = 128.f * (float)cs_h * inv33 + bias;
        if (layer == 0) off += 128.f * (float)cs_x * inv30;
        offs[c] = off;
    }
    __syncthreads();

    const int mrow = (tid >> 6) * 32 + (lane & 31);   // batch row of A fragment
    const int ksub = (lane >> 5) * 16;                // k sub-offset (i16 units)

    for (int p = 0; p <= T_STEPS; ++p) {
        const bool active = (layer == 0) ? (p < T_STEPS) : (p >= 1);

        // ---- L0 x-projection BEFORE the wait (independent of phase p-1) ---
        float px[16];
        if (layer == 0 && active) {
            v16i ax = zero16(), mx = zero16();
            const short* axp = xq + ((size_t)mrow * 512 + p) * 256 + ksub;
#pragma unroll
            for (int s = 0; s < 8; ++s)
                kstep(axp + s * 32, wlds + s * 2048 + lane * 16, ax, mx);
#pragma unroll
            for (int r = 0; r < 16; ++r)
                px[r] = ((float)ax[r] * 65536.f + (float)mx[r] * 256.f) * inv30;
        }

        // ---- split-phase barrier wait (gen p), master-gather + bcast ------
        if (p > 0) {
            const unsigned pp = (unsigned)p;
            if (wg == 0) {
                const unsigned* s0 = gslots + (tid * 2) * 16;
                const unsigned* s1 = s0 + 16;
                while (__hip_atomic_load(s0, __ATOMIC_RELAXED, __HIP_MEMORY_SCOPE_AGENT) < pp)
                    __builtin_amdgcn_s_sleep(1);
                while (__hip_atomic_load(s1, __ATOMIC_RELAXED, __HIP_MEMORY_SCOPE_AGENT) < pp)
                    __builtin_amdgcn_s_sleep(1);
                __syncthreads();
                __hip_atomic_store(gbcast + (tid * 2) * 16, pp, __ATOMIC_RELAXED, __HIP_MEMORY_SCOPE_AGENT);
                __hip_atomic_store(gbcast + (tid * 2 + 1) * 16, pp, __ATOMIC_RELAXED, __HIP_MEMORY_SCOPE_AGENT);
            } else {
                if (tid == 0) {
                    while (__hip_atomic_load(gbcast + wg * 16, __ATOMIC_RELAXED, __HIP_MEMORY_SCOPE_AGENT) < pp)
                        __builtin_amdgcn_s_sleep(1);
                }
            }
            __syncthreads();
            asm volatile("" ::: "memory");
        }

        if (active) {
            const short* hprev = h0q + ((p + 1) & 1) * 65536 + mrow * 1024 + ksub; // h0(p-1)
            float gates[16];
            v16i ahh = zero16(), amid = zero16();
            v4i b0[16], b1[16];
            if (layer == 0) {
                // h segment (K=1024, ksteps 8..39), double-buffered pipeline
                if (p > 0) {
                    waitcnt0();   // drain stray vmcnt (x loads / poll) before counting
                    const char* W = wlds + lane * 16;
                    load_h16_nw(hprev, b0);
                    load_h16_nw(hprev + 256, b1);
                    WAIT_BIND("16", b0); consume8(b0, W + 8 * 2048, ahh, amid);
                    load_h16_nw(hprev + 512, b0);
                    WAIT_BIND("16", b1); consume8(b1, W + 16 * 2048, ahh, amid);
                    load_h16_nw(hprev + 768, b1);
                    WAIT_BIND("16", b0); consume8(b0, W + 24 * 2048, ahh, amid);
                    WAIT_BIND("0", b1);  consume8(b1, W + 32 * 2048, ahh, amid);
                }
#pragma unroll
                for (int r = 0; r < 16; ++r)
                    gates[r] = px[r]
                             + ((float)ahh[r] * 65536.f + (float)amid[r] * 256.f) * inv33
                             + offs[lane & 31];
            } else {
                // layer1: h0(p-1) (ksteps 0..31) then h2(p-2) (ksteps 32..63)
                const short* h2p = h2q + ((p + 1) & 1) * 65536 + mrow * 1024 + ksub;
                waitcnt0();
                const char* W = wlds + lane * 16;
                load_h16_nw(hprev, b0);
                load_h16_nw(hprev + 256, b1);
                WAIT_BIND("16", b0); consume8(b0, W, ahh, amid);
                load_h16_nw(hprev + 512, b0);
                WAIT_BIND("16", b1); consume8(b1, W + 8 * 2048, ahh, amid);
                load_h16_nw(hprev + 768, b1);
                WAIT_BIND("16", b0); consume8(b0, W + 16 * 2048, ahh, amid);
                load_h16_nw(h2p, b0);
                WAIT_BIND("16", b1); consume8(b1, W + 24 * 2048, ahh, amid);
                load_h16_nw(h2p + 256, b1);
                WAIT_BIND("16", b0); consume8(b0, W + 32 * 2048, ahh, amid);
                load_h16_nw(h2p + 512, b0);
                WAIT_BIND("16", b1); consume8(b1, W + 40 * 2048, ahh, amid);
                load_h16_nw(h2p + 768, b1);
                WAIT_BIND("16", b0); consume8(b0, W + 48 * 2048, ahh, amid);
                WAIT_BIND("0", b1);  consume8(b1, W + 56 * 2048, ahh, amid);
#pragma unroll
                for (int r = 0; r < 16; ++r)
                    gates[r] = ((float)ahh[r] * 65536.f + (float)amid[r] * 256.f) * inv33
                             + offs[lane & 31];
            }
            // scatter C/D frag to LDS: col=lane&31, row=(r&3)+8*(r>>2)+4*(lane>>5)
            {
                const int rbase = (tid >> 6) * 32 + 4 * (lane >> 5);
                const int c = lane & 31;
#pragma unroll
                for (int r = 0; r < 16; ++r) {
                    int row = rbase + (r & 3) + 8 * (r >> 2);
                    gbuf[row * 33 + c] = gates[r];
                }
            }
        }
        __syncthreads();
        if (active) {
            // state update: thread = (row, unit quad); one 8B MALL store each.
            short* hw = ((layer == 0) ? h0q : h2q) + (p & 1) * 65536;
            const int r    = tid & 63;
            const int half = tid >> 6;
            unsigned hq[4];
            float hf[4];
#pragma unroll
            for (int j = 0; j < 4; ++j) {
                const int u = half * 4 + j;
                const float gi = gbuf[r * 33 + 4 * u + 0];
                const float gf = gbuf[r * 33 + 4 * u + 1];
                const float gg = gbuf[r * 33 + 4 * u + 2];
                const float go = gbuf[r * 33 + 4 * u + 3];
                const float i_ = 1.f / (1.f + __expf(-gi));
                const float f_ = 1.f / (1.f + __expf(-gf));
                const float g_ = 1.f - 2.f / (__expf(2.f * gg) + 1.f);
                const float o_ = 1.f / (1.f + __expf(-go));
                float c_ = f_ * cbuf[r * 9 + u] + i_ * g_;
                cbuf[r * 9 + u] = c_;
                const float h_ = o_ * (1.f - 2.f / (__expf(2.f * c_) + 1.f));
                hq[j] = (unsigned)(unsigned short)(short)__float2int_rn(h_ * 16384.f);
                hf[j] = h_;
            }
            v2i pk;
            pk.x = (int)(hq[0] | (hq[1] << 16));
            pk.y = (int)(hq[2] | (hq[3] << 16));
            const int jg = nblk * 8 + half * 4;
            store_h8(hw + r * 1024 + jg, pk);
            if (layer == 1 && p == T_STEPS) {
#pragma unroll
                for (int j = 0; j < 4; ++j) h2f[r * 1024 + jg + j] = hf[j];
            }
        }
        // ---- arrival (gen p+1); skip after the final phase ----------------
        if (p < T_STEPS) {
            waitcnt0();
            __syncthreads();
            if (tid == 0)
                __hip_atomic_store(gslots + wg * 16, (unsigned)(p + 1),
                                   __ATOMIC_RELAXED, __HIP_MEMORY_SCOPE_AGENT);
        }
    }
}

// ---------------------------------------------------------------------------
__global__ void final_lin(const float* __restrict__ h2f, const float* __restrict__ wlin,
                          const float* __restrict__ blin, float* __restrict__ out)
{
    const int b = blockIdx.x;
    const int l = threadIdx.x;
    float s = 0.f;
    for (int j = l; j < 1024; j += 64) s += h2f[b * 1024 + j] * wlin[j];
#pragma unroll
    for (int off = 32; off; off >>= 1) s += __shfl_down(s, off);
    if (l == 0) out[b] = s + blin[0];
}

// ---------------------------------------------------------------------------
extern "C" void kernel_launch(void* const* d_in, const int* in_sizes, int n_in,
                              void* d_out, int out_size, void* d_ws, size_t ws_size,
                              hipStream_t stream)
{
    const float* x    = (const float*)d_in[0];
    const float* wih0 = (const float*)d_in[1];
    const float* whh0 = (const float*)d_in[2];
    const float* bih0 = (const float*)d_in[3];
    const float* bhh0 = (const float*)d_in[4];
    const float* wih1 = (const float*)d_in[5];
    const float* whh1 = (const float*)d_in[6];
    const float* bih1 = (const float*)d_in[7];
    const float* bhh1 = (const float*)d_in[8];
    const float* wlin = (const float*)d_in[9];
    const float* blin = (const float*)d_in[10];

    // workspace layout (R3's)
    char* ws = (char*)d_ws;
    unsigned* gslots = (unsigned*)ws;                    // 256 x 64B
    unsigned* gbcast = (unsigned*)(ws + 16384);          // 256 x 64B
    short* h0q = (short*)(ws + 65536);                   // [2][64][1024] i16 = 256KB
    short* h2q = (short*)(ws + 65536 + 262144);          // 256KB
    float* h2f = (float*)(ws + 65536 + 524288);          // [64][1024] f32 = 256KB
    short* xq  = (short*)(ws + 65536 + 786432);          // 16MB
    char*  wimg = ws + 65536 + 786432 + 16777216;        // 256 * 128KB = 32MB

    // zero barrier state + h ping-pong buffers (ws re-poisoned 0xAA each call)
    hipMemsetAsync(ws, 0, 65536 + 524288, stream);

    quant_x<<<32768, 256, 0, stream>>>(x, xq, 64 * 512 * 256);
    quant_w<<<4096, 256, 0, stream>>>(wih0, whh0, wih1, whh1, wimg);

    hipFuncSetAttribute((const void*)lstm_main,
        hipFuncAttributeMaxDynamicSharedMemorySize, SMEM_BYTES);

    lstm_main<<<NWG, 128, SMEM_BYTES, stream>>>(xq, wimg, bih0, bhh0, bih1, bhh1,
                                                h0q, h2q, h2f, gslots, gbcast);
    final_lin<<<64, 64, 0, stream>>>(h2f, wlin, blin, (float*)d_out);
}